// Round 3
// baseline (112.332 us; speedup 1.0000x reference)
//
#include <hip/hip_runtime.h>
#include <stdint.h>

#define N_AGENTS 4096
#define TOPK 12
#define EPSF 1e-4f
#define ROWS 8              // rows per block
#define EDGES (ROWS * TOPK) // 96 edges per block
#define SCAP 128            // survivor capacity per row

typedef unsigned long long u64;
typedef _Float16 half8 __attribute__((ext_vector_type(8)));
typedef float floatx4 __attribute__((ext_vector_type(4)));

static __device__ __forceinline__ u64 umin64(u64 a, u64 b) { return a < b ? a : b; }

// ---- 32-bit cross-lane xor exchange (J<=16 swizzle, J=32 bpermute) ----
template <int J>
static __device__ __forceinline__ uint32_t xswap32(uint32_t v, int bpaddr) {
    if constexpr (J == 32) {
        return (uint32_t)__builtin_amdgcn_ds_bpermute(bpaddr, (int)v);
    } else {
        constexpr int imm = 0x1F | (J << 10);
        return (uint32_t)__builtin_amdgcn_ds_swizzle((int)v, imm);
    }
}

// Paired compare-exchange stage: two independent bitonic networks advance in
// lockstep so the two swizzle latencies overlap (ILP).
template <int K, int J>
static __device__ __forceinline__ void ce2(uint32_t& a, uint32_t& b, int lane, int bpaddr) {
    const uint32_t oa = xswap32<J>(a, bpaddr);
    const uint32_t ob = xswap32<J>(b, bpaddr);
    const bool up = (K == 64) ? true : ((lane & K) == 0);
    const bool keepmin = (((lane & J) == 0) == up);
    const uint32_t mna = a < oa ? a : oa;
    const uint32_t mxa = a < oa ? oa : a;
    const uint32_t mnb = b < ob ? b : ob;
    const uint32_t mxb = b < ob ? ob : b;
    a = keepmin ? mna : mxa;
    b = keepmin ? mnb : mxb;
}

static __device__ __forceinline__ void bitonic64_u32x2(uint32_t& a, uint32_t& b, int lane, int bpaddr) {
    ce2<2, 1>(a, b, lane, bpaddr);
    ce2<4, 2>(a, b, lane, bpaddr);
    ce2<4, 1>(a, b, lane, bpaddr);
    ce2<8, 4>(a, b, lane, bpaddr);
    ce2<8, 2>(a, b, lane, bpaddr);
    ce2<8, 1>(a, b, lane, bpaddr);
    ce2<16, 8>(a, b, lane, bpaddr);
    ce2<16, 4>(a, b, lane, bpaddr);
    ce2<16, 2>(a, b, lane, bpaddr);
    ce2<16, 1>(a, b, lane, bpaddr);
    ce2<32, 16>(a, b, lane, bpaddr);
    ce2<32, 8>(a, b, lane, bpaddr);
    ce2<32, 4>(a, b, lane, bpaddr);
    ce2<32, 2>(a, b, lane, bpaddr);
    ce2<32, 1>(a, b, lane, bpaddr);
    ce2<64, 32>(a, b, lane, bpaddr);
    ce2<64, 16>(a, b, lane, bpaddr);
    ce2<64, 8>(a, b, lane, bpaddr);
    ce2<64, 4>(a, b, lane, bpaddr);
    ce2<64, 2>(a, b, lane, bpaddr);
    ce2<64, 1>(a, b, lane, bpaddr);
}

// ---- 64-bit variants (exact final sort: key = (sqrt_bits<<32)|j) ----
template <int J>
static __device__ __forceinline__ u64 xswap64(u64 v, int bpaddr) {
    int lo = (int)(unsigned int)(v & 0xffffffffULL);
    int hi = (int)(unsigned int)(v >> 32);
    int nlo, nhi;
    if constexpr (J == 32) {
        nlo = __builtin_amdgcn_ds_bpermute(bpaddr, lo);
        nhi = __builtin_amdgcn_ds_bpermute(bpaddr, hi);
    } else {
        constexpr int imm = 0x1F | (J << 10);
        nlo = __builtin_amdgcn_ds_swizzle(lo, imm);
        nhi = __builtin_amdgcn_ds_swizzle(hi, imm);
    }
    return ((u64)(unsigned int)nhi << 32) | (unsigned int)nlo;
}

template <int K, int J>
static __device__ __forceinline__ u64 ce_stage(u64 v, int lane, int bpaddr) {
    const u64 o = xswap64<J>(v, bpaddr);
    const bool up = (K == 64) ? true : ((lane & K) == 0);
    const bool keepmin = (((lane & J) == 0) == up);
    const bool lt = v < o;
    const u64 mn = lt ? v : o;
    const u64 mx = lt ? o : v;
    return keepmin ? mn : mx;
}

static __device__ __forceinline__ u64 bitonic64(u64 v, int lane, int bpaddr) {
    v = ce_stage<2, 1>(v, lane, bpaddr);
    v = ce_stage<4, 2>(v, lane, bpaddr);
    v = ce_stage<4, 1>(v, lane, bpaddr);
    v = ce_stage<8, 4>(v, lane, bpaddr);
    v = ce_stage<8, 2>(v, lane, bpaddr);
    v = ce_stage<8, 1>(v, lane, bpaddr);
    v = ce_stage<16, 8>(v, lane, bpaddr);
    v = ce_stage<16, 4>(v, lane, bpaddr);
    v = ce_stage<16, 2>(v, lane, bpaddr);
    v = ce_stage<16, 1>(v, lane, bpaddr);
    v = ce_stage<32, 16>(v, lane, bpaddr);
    v = ce_stage<32, 8>(v, lane, bpaddr);
    v = ce_stage<32, 4>(v, lane, bpaddr);
    v = ce_stage<32, 2>(v, lane, bpaddr);
    v = ce_stage<32, 1>(v, lane, bpaddr);
    v = ce_stage<64, 32>(v, lane, bpaddr);
    v = ce_stage<64, 16>(v, lane, bpaddr);
    v = ce_stage<64, 8>(v, lane, bpaddr);
    v = ce_stage<64, 4>(v, lane, bpaddr);
    v = ce_stage<64, 2>(v, lane, bpaddr);
    v = ce_stage<64, 1>(v, lane, bpaddr);
    return v;
}

static __device__ __forceinline__ u64 wavemin64(u64 v, int bpaddr) {
    v = umin64(v, xswap64<1>(v, bpaddr));
    v = umin64(v, xswap64<2>(v, bpaddr));
    v = umin64(v, xswap64<4>(v, bpaddr));
    v = umin64(v, xswap64<8>(v, bpaddr));
    v = umin64(v, xswap64<16>(v, bpaddr));
    v = umin64(v, xswap64<32>(v, bpaddr));
    return v;
}

// Fully fused: one block owns ROWS=8 agents. Phases (barrier-separated):
//  A) scan all 4096 agents in d^2 domain (uint order == float order), keep
//     d2[8][16] in regs, per-thread row-minima -> LDS.
//  B) per wave (2 rows): combine 4 thread-minima (each min over 64 disjoint
//     points) -> 64 values; paired bitonic; 12th smallest = provable upper
//     bound on the row's 12th smallest d^2 (12 distinct candidates <= it).
//  C) threshold pass from regs (no recompute); survivors get sqrt; key
//     (sqrt_bits<<32)|j is bit-identical to the reference ordering (ties by
//     lower j, matching jax.lax.top_k stability). +8-ulp slack on U covers
//     the sqrt tie-class preimage.
//  D) per-row exact 64-bit bitonic sort of survivors -> dist/idx in LDS.
//  MLP) L1 fp32 VALU; L2/L3 f16 MFMA 16x16x32 (fp32 accum); L4 swizzle
//     reduction — operation-for-operation identical to the verified split
//     kernel (bit-identical output). B-fragments gathered from f32 W2/W3
//     with the same RTN f32->f16 cast (L2-resident; issued early to hide
//     latency under phase D).
// LDS: survivor arena (lmin+surv, 16 KB) is temporally aliased with
// h1s/h2s (40 KB) — barrier-separated. Total ~42 KB -> 2 blocks/CU at 512
// blocks (exactly resident).
__global__ __launch_bounds__(256) void fused_kernel(
    const float* __restrict__ states,
    const float* __restrict__ W1, const float* __restrict__ b1,
    const float* __restrict__ W2, const float* __restrict__ b2,
    const float* __restrict__ W3, const float* __restrict__ b3,
    const float* __restrict__ W4, const float* __restrict__ b4,
    float* __restrict__ out) {
    __shared__ __align__(16) char smem[13824 + 26112];  // h1s[96][72] + h2s[96][136]
    uint32_t(*lmin)[256] = (uint32_t(*)[256])smem;      // 8 KB   (aliases h1s)
    u64(*surv)[SCAP] = (u64(*)[SCAP])(smem + 8192);     // 8 KB   (aliases h1s/h2s)
    _Float16* h1s = (_Float16*)smem;
    _Float16* h2s = (_Float16*)(smem + 13824);
    __shared__ float dist_l[EDGES];
    __shared__ int idx_l[EDGES];
    __shared__ uint32_t Ub[ROWS];
    __shared__ int cnt[ROWS];
    __shared__ float partial[4 * EDGES];

    const int t = threadIdx.x;
    const int lane = t & 63;
    const int wv = __builtin_amdgcn_readfirstlane(t >> 6);
    const int quad = lane >> 4;
    const int l15 = lane & 15;
    const int bpaddr = (lane ^ 32) << 2;
    const int i0 = blockIdx.x * ROWS;
    const float2* st2 = (const float2*)states;  // [j*2] = (x,y)

    // ---- Phase A: distance scan (d^2 domain)
    float2 me[ROWS];
#pragma unroll
    for (int r = 0; r < ROWS; ++r) me[r] = st2[(i0 + r) * 2];

    uint32_t d2[ROWS][16];
#pragma unroll
    for (int s = 0; s < 16; ++s) {
        const float2 p = st2[(t + s * 256) * 2];
#pragma unroll
        for (int r = 0; r < ROWS; ++r) {
            const float dx = me[r].x - p.x;
            const float dy = me[r].y - p.y;
            d2[r][s] = __float_as_uint((dx * dx + EPSF) + (dy * dy + EPSF));
        }
    }
#pragma unroll
    for (int r = 0; r < ROWS; ++r) {
        uint32_t mn = d2[r][0];
#pragma unroll
        for (int s = 1; s < 16; ++s) mn = d2[r][s] < mn ? d2[r][s] : mn;
        lmin[r][t] = mn;
    }
    if (t < ROWS) cnt[t] = 0;
    __syncthreads();

    // ---- Phase B: per-wave bound for rows 2wv, 2wv+1
    {
        const int r0 = wv * 2, r1 = r0 + 1;
        uint32_t a0 = lmin[r0][lane];
        uint32_t x;
        x = lmin[r0][lane + 64];  a0 = x < a0 ? x : a0;
        x = lmin[r0][lane + 128]; a0 = x < a0 ? x : a0;
        x = lmin[r0][lane + 192]; a0 = x < a0 ? x : a0;
        uint32_t a1 = lmin[r1][lane];
        x = lmin[r1][lane + 64];  a1 = x < a1 ? x : a1;
        x = lmin[r1][lane + 128]; a1 = x < a1 ? x : a1;
        x = lmin[r1][lane + 192]; a1 = x < a1 ? x : a1;
        bitonic64_u32x2(a0, a1, lane, bpaddr);
        if (lane == 11) {
            Ub[r0] = a0;
            Ub[r1] = a1;
        }
    }
    __syncthreads();

    // ---- Phase C: survivor collection (threshold from registers)
#pragma unroll
    for (int r = 0; r < ROWS; ++r) {
        const uint32_t Ur = Ub[r] + 8;  // sqrt tie-class slack
#pragma unroll
        for (int s = 0; s < 16; ++s) {
            if (d2[r][s] <= Ur) {
                const int p = atomicAdd(&cnt[r], 1);
                if (p < SCAP) {
                    const uint32_t sb = __float_as_uint(sqrtf(__uint_as_float(d2[r][s])));
                    surv[r][p] = ((u64)sb << 32) | (unsigned int)(t + s * 256);
                }
            }
        }
    }
    __syncthreads();

    // ---- W2/W3 B-fragment gathers (f32 -> f16 RTN, identical to repack);
    // issued here so the ~200cy L2 latency hides under phase D's swizzles.
    half8 b2f[2][2], b3f[4];
#pragma unroll
    for (int ks = 0; ks < 2; ++ks)
#pragma unroll
        for (int nt = 0; nt < 2; ++nt) {
            const int n = wv * 32 + nt * 16 + l15;
            const float* p = W2 + (ks * 32 + quad * 8) * 128 + n;
            half8 f;
#pragma unroll
            for (int jj = 0; jj < 8; ++jj) f[jj] = (_Float16)p[jj * 128];
            b2f[ks][nt] = f;
        }
    const int n3 = wv * 16 + l15;
#pragma unroll
    for (int ks = 0; ks < 4; ++ks) {
        const float* p3 = W3 + (ks * 32 + quad * 8) * 64 + n3;
        half8 f;
#pragma unroll
        for (int jj = 0; jj < 8; ++jj) f[jj] = (_Float16)p3[jj * 64];
        b3f[ks] = f;
    }

    // ---- Phase D: per-wave exact final sort of rows 2wv, 2wv+1
    for (int rr = 0; rr < 2; ++rr) {
        const int r = wv * 2 + rr;
        const int S = cnt[r];
        if (S <= 64) {
            u64 v = (lane < S) ? surv[r][lane] : ~0ULL;
            v = bitonic64(v, lane, bpaddr);
            if (lane < TOPK) {
                idx_l[r * TOPK + lane] = (int)(unsigned int)(v & 0xffffffffULL);
                dist_l[r * TOPK + lane] = __uint_as_float((unsigned int)(v >> 32));
            }
        } else {
            // cold fallback (S in (64, 128]): iterative extraction
            u64 a0 = (lane < S) ? surv[r][lane] : ~0ULL;
            u64 a1 = (lane + 64 < S) ? surv[r][lane + 64] : ~0ULL;
            u64 al = umin64(a0, a1);
            for (int k = 0; k < TOPK; ++k) {
                const u64 v = wavemin64(al, bpaddr);
                if (lane == 0) {
                    idx_l[r * TOPK + k] = (int)(unsigned int)(v & 0xffffffffULL);
                    dist_l[r * TOPK + k] = __uint_as_float((unsigned int)(v >> 32));
                }
                if (al == v) {
                    if (a0 == v) a0 = ~0ULL;
                    if (a1 == v) a1 = ~0ULL;
                    al = umin64(a0, a1);
                }
            }
        }
    }
    __syncthreads();  // surv/lmin dead; h1s arena reuse begins

    // ---- MLP L1 (fp32): threads 0..127 do outputs [0,32), 128..255 do [32,64)
    const int eL = t & 127;
    const int o0 = (t >> 7) * 32;
    float d_edge = 0.0f;
    if (eL < EDGES) {
        const int i = i0 + eL / TOPK;
        const int j = idx_l[eL];
        d_edge = dist_l[eL];
        const float4 si = ((const float4*)states)[i];
        const float4 sj = ((const float4*)states)[j];
        float feat[6];
        feat[0] = si.x - sj.x;
        feat[1] = si.y - sj.y;
        feat[2] = si.z - sj.z;
        feat[3] = si.w - sj.w;
        feat[4] = (i == j) ? 1.0f : 0.0f;
        feat[5] = d_edge - 0.1f;

        _Float16 h1v[32];
#pragma unroll
        for (int oo = 0; oo < 32; ++oo) {
            const int o = o0 + oo;
            float acc = b1[o];
#pragma unroll
            for (int f = 0; f < 6; ++f) acc += feat[f] * W1[f * 64 + o];
            h1v[oo] = (_Float16)fmaxf(acc, 0.0f);
        }
        half8* dst = (half8*)&h1s[eL * 72 + o0];
        dst[0] = *(half8*)&h1v[0];
        dst[1] = *(half8*)&h1v[8];
        dst[2] = *(half8*)&h1v[16];
        dst[3] = *(half8*)&h1v[24];
    }
    __syncthreads();

    // ---- L2 (MFMA): C[m=96][n=wv*32 .. +32]
    floatx4 acc2[6][2];
#pragma unroll
    for (int mt = 0; mt < 6; ++mt)
#pragma unroll
        for (int nt = 0; nt < 2; ++nt) acc2[mt][nt] = (floatx4){0.f, 0.f, 0.f, 0.f};
#pragma unroll
    for (int ks = 0; ks < 2; ++ks)
#pragma unroll
        for (int mt = 0; mt < 6; ++mt) {
            const half8 a = *(const half8*)&h1s[(mt * 16 + l15) * 72 + ks * 32 + quad * 8];
            acc2[mt][0] = __builtin_amdgcn_mfma_f32_16x16x32_f16(a, b2f[ks][0], acc2[mt][0], 0, 0, 0);
            acc2[mt][1] = __builtin_amdgcn_mfma_f32_16x16x32_f16(a, b2f[ks][1], acc2[mt][1], 0, 0, 0);
        }
    float bias2[2] = {b2[wv * 32 + l15], b2[wv * 32 + 16 + l15]};
#pragma unroll
    for (int mt = 0; mt < 6; ++mt)
#pragma unroll
        for (int nt = 0; nt < 2; ++nt)
#pragma unroll
            for (int r = 0; r < 4; ++r) {
                const int m = mt * 16 + quad * 4 + r;
                const int n = wv * 32 + nt * 16 + l15;
                h2s[m * 136 + n] = (_Float16)fmaxf(acc2[mt][nt][r] + bias2[nt], 0.0f);
            }
    __syncthreads();

    // ---- L3 (MFMA): C[m=96][n=wv*16 .. +16]
    floatx4 acc3[6];
#pragma unroll
    for (int mt = 0; mt < 6; ++mt) acc3[mt] = (floatx4){0.f, 0.f, 0.f, 0.f};
#pragma unroll
    for (int ks = 0; ks < 4; ++ks)
#pragma unroll
        for (int mt = 0; mt < 6; ++mt) {
            const half8 a = *(const half8*)&h2s[(mt * 16 + l15) * 136 + ks * 32 + quad * 8];
            acc3[mt] = __builtin_amdgcn_mfma_f32_16x16x32_f16(a, b3f[ks], acc3[mt], 0, 0, 0);
        }

    // ---- L4: per-lane relu+dot, reduce over the 16 n's in each quad
    const float bias3 = b3[n3];
    const float w4v = W4[n3];
#pragma unroll
    for (int mt = 0; mt < 6; ++mt)
#pragma unroll
        for (int r = 0; r < 4; ++r) {
            float v = fmaxf(acc3[mt][r] + bias3, 0.0f) * w4v;
            v += __int_as_float(__builtin_amdgcn_ds_swizzle(__float_as_int(v), 0x041F));
            v += __int_as_float(__builtin_amdgcn_ds_swizzle(__float_as_int(v), 0x081F));
            v += __int_as_float(__builtin_amdgcn_ds_swizzle(__float_as_int(v), 0x101F));
            v += __int_as_float(__builtin_amdgcn_ds_swizzle(__float_as_int(v), 0x201F));
            if (l15 == 0) partial[wv * EDGES + mt * 16 + quad * 4 + r] = v;
        }
    __syncthreads();

    if (t < EDGES) {  // t == eL here, d_edge already in register
        const float s =
            partial[t] + partial[EDGES + t] + partial[2 * EDGES + t] + partial[3 * EDGES + t] + b4[0];
        out[blockIdx.x * EDGES + t] = (d_edge <= 1.0f) ? s : 0.0f;
    }
}

extern "C" void kernel_launch(void* const* d_in, const int* in_sizes, int n_in,
                              void* d_out, int out_size, void* d_ws, size_t ws_size,
                              hipStream_t stream) {
    const float* states = (const float*)d_in[0];
    const float* W1 = (const float*)d_in[1];
    const float* b1 = (const float*)d_in[2];
    const float* W2 = (const float*)d_in[3];
    const float* b2 = (const float*)d_in[4];
    const float* W3 = (const float*)d_in[5];
    const float* b3 = (const float*)d_in[6];
    const float* W4 = (const float*)d_in[7];
    const float* b4 = (const float*)d_in[8];

    fused_kernel<<<N_AGENTS / ROWS, 256, 0, stream>>>(
        states, W1, b1, W2, b2, W3, b3, W4, b4, (float*)d_out);
}

// Round 4
// 100.482 us; speedup vs baseline: 1.1179x; 1.1179x over previous
//
#include <hip/hip_runtime.h>
#include <stdint.h>

#define N_AGENTS 4096
#define TOPK 12
#define EPSF 1e-4f
#define SURV_CAP 256
#define EDGES_B 24  // 2 rows * TOPK edges per block

typedef unsigned long long u64;
typedef _Float16 half8 __attribute__((ext_vector_type(8)));
typedef float floatx4 __attribute__((ext_vector_type(4)));

static __device__ __forceinline__ u64 umin64(u64 a, u64 b) { return a < b ? a : b; }

// ---- 32-bit cross-lane xor exchange (J<=16 swizzle, J=32 bpermute) ----
template <int J>
static __device__ __forceinline__ uint32_t xswap32(uint32_t v, int bpaddr) {
    if constexpr (J == 32) {
        return (uint32_t)__builtin_amdgcn_ds_bpermute(bpaddr, (int)v);
    } else {
        constexpr int imm = 0x1F | (J << 10);
        return (uint32_t)__builtin_amdgcn_ds_swizzle((int)v, imm);
    }
}

// Paired compare-exchange stage: two independent bitonic networks advance in
// lockstep so the two swizzle latencies overlap (ILP).
template <int K, int J>
static __device__ __forceinline__ void ce2(uint32_t& a, uint32_t& b, int lane, int bpaddr) {
    const uint32_t oa = xswap32<J>(a, bpaddr);
    const uint32_t ob = xswap32<J>(b, bpaddr);
    const bool up = (K == 64) ? true : ((lane & K) == 0);
    const bool keepmin = (((lane & J) == 0) == up);
    const uint32_t mna = a < oa ? a : oa;
    const uint32_t mxa = a < oa ? oa : a;
    const uint32_t mnb = b < ob ? b : ob;
    const uint32_t mxb = b < ob ? ob : b;
    a = keepmin ? mna : mxa;
    b = keepmin ? mnb : mxb;
}

static __device__ __forceinline__ void bitonic64_u32x2(uint32_t& a, uint32_t& b, int lane, int bpaddr) {
    ce2<2, 1>(a, b, lane, bpaddr);
    ce2<4, 2>(a, b, lane, bpaddr);
    ce2<4, 1>(a, b, lane, bpaddr);
    ce2<8, 4>(a, b, lane, bpaddr);
    ce2<8, 2>(a, b, lane, bpaddr);
    ce2<8, 1>(a, b, lane, bpaddr);
    ce2<16, 8>(a, b, lane, bpaddr);
    ce2<16, 4>(a, b, lane, bpaddr);
    ce2<16, 2>(a, b, lane, bpaddr);
    ce2<16, 1>(a, b, lane, bpaddr);
    ce2<32, 16>(a, b, lane, bpaddr);
    ce2<32, 8>(a, b, lane, bpaddr);
    ce2<32, 4>(a, b, lane, bpaddr);
    ce2<32, 2>(a, b, lane, bpaddr);
    ce2<32, 1>(a, b, lane, bpaddr);
    ce2<64, 32>(a, b, lane, bpaddr);
    ce2<64, 16>(a, b, lane, bpaddr);
    ce2<64, 8>(a, b, lane, bpaddr);
    ce2<64, 4>(a, b, lane, bpaddr);
    ce2<64, 2>(a, b, lane, bpaddr);
    ce2<64, 1>(a, b, lane, bpaddr);
}

// ---- 64-bit variants (exact final sort: key = (sqrt_bits<<32)|j) ----
template <int J>
static __device__ __forceinline__ u64 xswap64(u64 v, int bpaddr) {
    int lo = (int)(unsigned int)(v & 0xffffffffULL);
    int hi = (int)(unsigned int)(v >> 32);
    int nlo, nhi;
    if constexpr (J == 32) {
        nlo = __builtin_amdgcn_ds_bpermute(bpaddr, lo);
        nhi = __builtin_amdgcn_ds_bpermute(bpaddr, hi);
    } else {
        constexpr int imm = 0x1F | (J << 10);
        nlo = __builtin_amdgcn_ds_swizzle(lo, imm);
        nhi = __builtin_amdgcn_ds_swizzle(hi, imm);
    }
    return ((u64)(unsigned int)nhi << 32) | (unsigned int)nlo;
}

template <int K, int J>
static __device__ __forceinline__ u64 ce_stage(u64 v, int lane, int bpaddr) {
    const u64 o = xswap64<J>(v, bpaddr);
    const bool up = (K == 64) ? true : ((lane & K) == 0);
    const bool keepmin = (((lane & J) == 0) == up);
    const bool lt = v < o;
    const u64 mn = lt ? v : o;
    const u64 mx = lt ? o : v;
    return keepmin ? mn : mx;
}

static __device__ __forceinline__ u64 bitonic64(u64 v, int lane, int bpaddr) {
    v = ce_stage<2, 1>(v, lane, bpaddr);
    v = ce_stage<4, 2>(v, lane, bpaddr);
    v = ce_stage<4, 1>(v, lane, bpaddr);
    v = ce_stage<8, 4>(v, lane, bpaddr);
    v = ce_stage<8, 2>(v, lane, bpaddr);
    v = ce_stage<8, 1>(v, lane, bpaddr);
    v = ce_stage<16, 8>(v, lane, bpaddr);
    v = ce_stage<16, 4>(v, lane, bpaddr);
    v = ce_stage<16, 2>(v, lane, bpaddr);
    v = ce_stage<16, 1>(v, lane, bpaddr);
    v = ce_stage<32, 16>(v, lane, bpaddr);
    v = ce_stage<32, 8>(v, lane, bpaddr);
    v = ce_stage<32, 4>(v, lane, bpaddr);
    v = ce_stage<32, 2>(v, lane, bpaddr);
    v = ce_stage<32, 1>(v, lane, bpaddr);
    v = ce_stage<64, 32>(v, lane, bpaddr);
    v = ce_stage<64, 16>(v, lane, bpaddr);
    v = ce_stage<64, 8>(v, lane, bpaddr);
    v = ce_stage<64, 4>(v, lane, bpaddr);
    v = ce_stage<64, 2>(v, lane, bpaddr);
    v = ce_stage<64, 1>(v, lane, bpaddr);
    return v;
}

static __device__ __forceinline__ u64 wavemin64(u64 v, int bpaddr) {
    v = umin64(v, xswap64<1>(v, bpaddr));
    v = umin64(v, xswap64<2>(v, bpaddr));
    v = umin64(v, xswap64<4>(v, bpaddr));
    v = umin64(v, xswap64<8>(v, bpaddr));
    v = umin64(v, xswap64<16>(v, bpaddr));
    v = umin64(v, xswap64<32>(v, bpaddr));
    return v;
}

// Single fused kernel at the PROVEN round-2 geometry: 2 rows per block,
// 2048 blocks, ~18 KB LDS, scan regs 2x16 -> high occupancy preserved
// (the ROWS=8 fusion collapsed to 2 blocks/CU and was latency-bound).
// Phases:
//  A) d^2 scan (uint order == float order), dA/dB[16] kept in regs.
//  B) per-wave paired bitonic of lane-minima; sorted[11] = provable upper
//     bound on the row's 12th smallest d^2 (12 disjoint 16-point groups'
//     minima are 12 distinct candidates <= it); U = min over 4 waves.
//  C) survivor collection from regs; sqrt only for survivors; key
//     (sqrt_bits<<32)|j reproduces reference ordering exactly (ties by
//     lower j). +8-ulp slack covers the sqrt tie-class preimage.
//  D) waves 0/1: exact 64-bit bitonic sort -> idx/dist in LDS (no global
//     round-trip). W2/W3 B-fragment gathers issued before D to hide L2
//     latency under the swizzle chains.
//  MLP) own 24 edges, m-tile padded to 32 (pad h1 rows zeroed; pad C rows
//     discarded). L1 fp32 VALU; L2/L3 f16 MFMA 16x16x32 fp32-accum; L4
//     swizzle reduce — op-for-op identical to the verified round-2 mlp
//     (bit-identical output).
__global__ __launch_bounds__(256) void fused_kernel(
    const float* __restrict__ states,
    const float* __restrict__ W1, const float* __restrict__ b1,
    const float* __restrict__ W2, const float* __restrict__ b2,
    const float* __restrict__ W3, const float* __restrict__ b3,
    const float* __restrict__ W4, const float* __restrict__ b4,
    float* __restrict__ out) {
    __shared__ uint32_t wb[2][4];
    __shared__ u64 surv[2][SURV_CAP];
    __shared__ int cnt[2];
    __shared__ float dist_l[EDGES_B];
    __shared__ int idx_l[EDGES_B];
    __shared__ __align__(16) _Float16 h1s[32 * 72];   // [m=edge(pad32)][k=64(+8)]
    __shared__ __align__(16) _Float16 h2s[32 * 136];  // [m=edge(pad32)][k=128(+8)]
    __shared__ float partial[4 * 32];

    const int t = threadIdx.x;
    const int lane = t & 63;
    const int wv = __builtin_amdgcn_readfirstlane(t >> 6);
    const int quad = lane >> 4;
    const int l15 = lane & 15;
    const int bpaddr = (lane ^ 32) << 2;
    const int i0 = blockIdx.x * 2;
    const float2* st2 = (const float2*)states;  // [j*2] = (x,y)

    // ---- Phase A: d^2 scan
    const float2 me0 = st2[i0 * 2];
    const float2 me1 = st2[(i0 + 1) * 2];
    uint32_t dA[16], dB[16];
#pragma unroll
    for (int s = 0; s < 16; ++s) {
        const float2 p = st2[(t + s * 256) * 2];
        {
            const float dx = me0.x - p.x;
            const float dy = me0.y - p.y;
            dA[s] = __float_as_uint((dx * dx + EPSF) + (dy * dy + EPSF));
        }
        {
            const float dx = me1.x - p.x;
            const float dy = me1.y - p.y;
            dB[s] = __float_as_uint((dx * dx + EPSF) + (dy * dy + EPSF));
        }
    }
    uint32_t l0 = dA[0], l1 = dB[0];
#pragma unroll
    for (int s = 1; s < 16; ++s) {
        l0 = dA[s] < l0 ? dA[s] : l0;
        l1 = dB[s] < l1 ? dB[s] : l1;
    }

    // ---- Phase B: per-wave 12th-order-statistic bound
    bitonic64_u32x2(l0, l1, lane, bpaddr);
    if (lane == 11) {
        wb[0][wv] = l0;
        wb[1][wv] = l1;
    }
    if (t < 2) cnt[t] = 0;
    __syncthreads();

    uint32_t U0 = wb[0][0];
    U0 = wb[0][1] < U0 ? wb[0][1] : U0;
    U0 = wb[0][2] < U0 ? wb[0][2] : U0;
    U0 = wb[0][3] < U0 ? wb[0][3] : U0;
    uint32_t U1 = wb[1][0];
    U1 = wb[1][1] < U1 ? wb[1][1] : U1;
    U1 = wb[1][2] < U1 ? wb[1][2] : U1;
    U1 = wb[1][3] < U1 ? wb[1][3] : U1;
    U0 += 8;  // sqrt tie-class slack
    U1 += 8;

    // ---- Phase C: survivor collection (threshold from registers)
#pragma unroll
    for (int s = 0; s < 16; ++s) {
        const unsigned int j = (unsigned int)(t + s * 256);
        if (dA[s] <= U0) {
            const int p = atomicAdd(&cnt[0], 1);
            if (p < SURV_CAP) {
                const uint32_t sb = __float_as_uint(sqrtf(__uint_as_float(dA[s])));
                surv[0][p] = ((u64)sb << 32) | j;
            }
        }
        if (dB[s] <= U1) {
            const int p = atomicAdd(&cnt[1], 1);
            if (p < SURV_CAP) {
                const uint32_t sb = __float_as_uint(sqrtf(__uint_as_float(dB[s])));
                surv[1][p] = ((u64)sb << 32) | j;
            }
        }
    }
    __syncthreads();

    // ---- W2/W3 B-fragment gathers (f32 -> f16 RTN; L2-resident weights),
    // issued before phase D so the ~200cy latency hides under the swizzles.
    half8 b2f[2][2], b3f[4];
#pragma unroll
    for (int ks = 0; ks < 2; ++ks)
#pragma unroll
        for (int nt = 0; nt < 2; ++nt) {
            const int n = wv * 32 + nt * 16 + l15;
            const float* p = W2 + (ks * 32 + quad * 8) * 128 + n;
            half8 f;
#pragma unroll
            for (int jj = 0; jj < 8; ++jj) f[jj] = (_Float16)p[jj * 128];
            b2f[ks][nt] = f;
        }
    const int n3 = wv * 16 + l15;
#pragma unroll
    for (int ks = 0; ks < 4; ++ks) {
        const float* p3 = W3 + (ks * 32 + quad * 8) * 64 + n3;
        half8 f;
#pragma unroll
        for (int jj = 0; jj < 8; ++jj) f[jj] = (_Float16)p3[jj * 64];
        b3f[ks] = f;
    }

    // ---- Phase D: waves 0/1 exact final sort of rows 0/1
    if (wv < 2) {
        const int r = wv;
        const int S = cnt[r];
        if (S <= 64) {
            u64 x = (lane < S) ? surv[r][lane] : ~0ULL;
            x = bitonic64(x, lane, bpaddr);
            if (lane < TOPK) {
                idx_l[r * TOPK + lane] = (int)(unsigned int)(x & 0xffffffffULL);
                dist_l[r * TOPK + lane] = __uint_as_float((unsigned int)(x >> 32));
            }
        } else {
            // cold fallback (S in (64, 256]): iterative extraction
            u64 a[4];
#pragma unroll
            for (int q = 0; q < 4; ++q)
                a[q] = (lane + 64 * q < S) ? surv[r][lane + 64 * q] : ~0ULL;
            u64 al = umin64(umin64(a[0], a[1]), umin64(a[2], a[3]));
            for (int k = 0; k < TOPK; ++k) {
                const u64 v = wavemin64(al, bpaddr);
                if (lane == 0) {
                    idx_l[r * TOPK + k] = (int)(unsigned int)(v & 0xffffffffULL);
                    dist_l[r * TOPK + k] = __uint_as_float((unsigned int)(v >> 32));
                }
                if (al == v) {
#pragma unroll
                    for (int q = 0; q < 4; ++q)
                        if (a[q] == v) a[q] = ~0ULL;
                    al = umin64(umin64(a[0], a[1]), umin64(a[2], a[3]));
                }
            }
        }
    }
    __syncthreads();

    // ---- MLP L1 (fp32): threads 0..191 -> edge t>>3, 8 outputs each;
    // threads 192..255 zero the pad rows 24..31.
    if (t < 192) {
        const int e = t >> 3;
        const int og = (t & 7) * 8;
        const int i = i0 + (e >= TOPK ? 1 : 0);
        const int j = idx_l[e];
        const float de = dist_l[e];
        const float4 si = ((const float4*)states)[i];
        const float4 sj = ((const float4*)states)[j];
        float feat[6];
        feat[0] = si.x - sj.x;
        feat[1] = si.y - sj.y;
        feat[2] = si.z - sj.z;
        feat[3] = si.w - sj.w;
        feat[4] = (i == j) ? 1.0f : 0.0f;
        feat[5] = de - 0.1f;

        _Float16 h1v[8];
#pragma unroll
        for (int oo = 0; oo < 8; ++oo) {
            const int o = og + oo;
            float acc = b1[o];
#pragma unroll
            for (int f = 0; f < 6; ++f) acc += feat[f] * W1[f * 64 + o];
            h1v[oo] = (_Float16)fmaxf(acc, 0.0f);
        }
        *(half8*)&h1s[e * 72 + og] = *(half8*)&h1v[0];
    } else {
        const int rt = t - 192;
        const int row = 24 + (rt >> 3);
        const int og = (rt & 7) * 8;
        *(half8*)&h1s[row * 72 + og] = (half8){0, 0, 0, 0, 0, 0, 0, 0};
    }
    __syncthreads();

    // ---- L2 (MFMA): C[m=32][n=wv*32 .. +32]
    floatx4 acc2[2][2];
#pragma unroll
    for (int mt = 0; mt < 2; ++mt)
#pragma unroll
        for (int nt = 0; nt < 2; ++nt) acc2[mt][nt] = (floatx4){0.f, 0.f, 0.f, 0.f};
#pragma unroll
    for (int ks = 0; ks < 2; ++ks)
#pragma unroll
        for (int mt = 0; mt < 2; ++mt) {
            const half8 a = *(const half8*)&h1s[(mt * 16 + l15) * 72 + ks * 32 + quad * 8];
            acc2[mt][0] = __builtin_amdgcn_mfma_f32_16x16x32_f16(a, b2f[ks][0], acc2[mt][0], 0, 0, 0);
            acc2[mt][1] = __builtin_amdgcn_mfma_f32_16x16x32_f16(a, b2f[ks][1], acc2[mt][1], 0, 0, 0);
        }
    float bias2[2] = {b2[wv * 32 + l15], b2[wv * 32 + 16 + l15]};
#pragma unroll
    for (int mt = 0; mt < 2; ++mt)
#pragma unroll
        for (int nt = 0; nt < 2; ++nt)
#pragma unroll
            for (int r = 0; r < 4; ++r) {
                const int m = mt * 16 + quad * 4 + r;
                const int n = wv * 32 + nt * 16 + l15;
                h2s[m * 136 + n] = (_Float16)fmaxf(acc2[mt][nt][r] + bias2[nt], 0.0f);
            }
    __syncthreads();

    // ---- L3 (MFMA): C[m=32][n=wv*16 .. +16]
    floatx4 acc3[2];
#pragma unroll
    for (int mt = 0; mt < 2; ++mt) acc3[mt] = (floatx4){0.f, 0.f, 0.f, 0.f};
#pragma unroll
    for (int ks = 0; ks < 4; ++ks)
#pragma unroll
        for (int mt = 0; mt < 2; ++mt) {
            const half8 a = *(const half8*)&h2s[(mt * 16 + l15) * 136 + ks * 32 + quad * 8];
            acc3[mt] = __builtin_amdgcn_mfma_f32_16x16x32_f16(a, b3f[ks], acc3[mt], 0, 0, 0);
        }

    // ---- L4: per-lane relu+dot, reduce over the 16 n's in each quad
    const float bias3 = b3[n3];
    const float w4v = W4[n3];
#pragma unroll
    for (int mt = 0; mt < 2; ++mt)
#pragma unroll
        for (int r = 0; r < 4; ++r) {
            float v = fmaxf(acc3[mt][r] + bias3, 0.0f) * w4v;
            v += __int_as_float(__builtin_amdgcn_ds_swizzle(__float_as_int(v), 0x041F));
            v += __int_as_float(__builtin_amdgcn_ds_swizzle(__float_as_int(v), 0x081F));
            v += __int_as_float(__builtin_amdgcn_ds_swizzle(__float_as_int(v), 0x101F));
            v += __int_as_float(__builtin_amdgcn_ds_swizzle(__float_as_int(v), 0x201F));
            if (l15 == 0) partial[wv * 32 + mt * 16 + quad * 4 + r] = v;
        }
    __syncthreads();

    if (t < EDGES_B) {
        const float s =
            partial[t] + partial[32 + t] + partial[64 + t] + partial[96 + t] + b4[0];
        out[blockIdx.x * EDGES_B + t] = (dist_l[t] <= 1.0f) ? s : 0.0f;
    }
}

extern "C" void kernel_launch(void* const* d_in, const int* in_sizes, int n_in,
                              void* d_out, int out_size, void* d_ws, size_t ws_size,
                              hipStream_t stream) {
    const float* states = (const float*)d_in[0];
    const float* W1 = (const float*)d_in[1];
    const float* b1 = (const float*)d_in[2];
    const float* W2 = (const float*)d_in[3];
    const float* b2 = (const float*)d_in[4];
    const float* W3 = (const float*)d_in[5];
    const float* b3 = (const float*)d_in[6];
    const float* W4 = (const float*)d_in[7];
    const float* b4 = (const float*)d_in[8];

    fused_kernel<<<N_AGENTS / 2, 256, 0, stream>>>(
        states, W1, b1, W2, b2, W3, b3, W4, b4, (float*)d_out);
}